// Round 5
// baseline (835.542 us; speedup 1.0000x reference)
//
#include <hip/hip_runtime.h>

#define N_NODES  100000
#define N_EDGES  1600000
#define DIM      128
#define N_GRAPHS 512

#define BW       512                         // nodes per bucket
#define NBUCK    ((N_NODES + BW - 1) / BW)   // 196
#define CAP      12288                       // max edges per bucket
#define NB_CHUNK 4096

#define GRID     512                         // co-resident by LDS (64KB -> 2/CU x 256)
#define NTHR     512

#define NT_BIN   ((N_EDGES + NB_CHUNK - 1) / NB_CHUNK)   // 391
#define NT_CVT   6250                                     // 12.8M / (512*4)
#define NT_WT    128                                      // 65536 / 512
#define NT0      (NT_BIN + NT_CVT + NT_WT)
#define NT_L     ((N_NODES + 127) / 128)                  // 782

typedef short  bf16x8 __attribute__((ext_vector_type(8)));
typedef float  f32x4  __attribute__((ext_vector_type(4)));

__device__ inline ushort f2bf(float f) {  // round-to-nearest-even
    union { float f; unsigned u; } v; v.f = f;
    unsigned r = v.u + 0x7FFFu + ((v.u >> 16) & 1u);
    return (ushort)(r >> 16);
}
__device__ inline float bf2f_lo(unsigned u) { union { unsigned u; float f; } v; v.u = u << 16; return v.f; }
__device__ inline float bf2f_hi(unsigned u) { union { unsigned u; float f; } v; v.u = u & 0xFFFF0000u; return v.f; }

// ---- grid sync: monotone counter, device-scope atomics, L2 wb/inv fences ----
__device__ __forceinline__ void gsync(int* cnt, int target) {
    __syncthreads();                       // drains vmcnt: block's stores issued
    if (threadIdx.x == 0) {
        __threadfence();                   // release: wb local L2 (device scope)
        atomicAdd(cnt, 1);
        while (atomicAdd(cnt, 0) < target) __builtin_amdgcn_s_sleep(16);
        __threadfence();                   // acquire: inv L1/L2-nc
    }
    __syncthreads();
}

// ---------------- layer tile: aggregate (to LDS) + MFMA GEMM ----------------
// MODE bit1 = relu + dinv-prescale epilogue; bit2 = scale-by-dinv[src] gather
// (layer 1, xb unscaled). Gather is at the compulsory-fetch line-rate floor
// (~191 MB @ 2.8 TB/s, confirmed across 4 schedules). NO atomics (R4 lesson).
#define ACC8(vv) do { \
    acc[0] += bf2f_lo((vv).x); acc[1] += bf2f_hi((vv).x); \
    acc[2] += bf2f_lo((vv).y); acc[3] += bf2f_hi((vv).y); \
    acc[4] += bf2f_lo((vv).z); acc[5] += bf2f_hi((vv).z); \
    acc[6] += bf2f_lo((vv).w); acc[7] += bf2f_hi((vv).w); } while (0)

#define ACC8S(vv, dd) do { \
    acc[0] = fmaf(bf2f_lo((vv).x), dd, acc[0]); acc[1] = fmaf(bf2f_hi((vv).x), dd, acc[1]); \
    acc[2] = fmaf(bf2f_lo((vv).y), dd, acc[2]); acc[3] = fmaf(bf2f_hi((vv).y), dd, acc[3]); \
    acc[4] = fmaf(bf2f_lo((vv).z), dd, acc[4]); acc[5] = fmaf(bf2f_hi((vv).z), dd, acc[5]); \
    acc[6] = fmaf(bf2f_lo((vv).w), dd, acc[6]); acc[7] = fmaf(bf2f_hi((vv).w), dd, acc[7]); } while (0)

template<bool GS>
__device__ __forceinline__ void gather_edges(const uint4* __restrict__ hp,
                                             const int* __restrict__ ssrc,
                                             const float* __restrict__ dv,
                                             int e, int end, int l, float* acc) {
    for (; e + 7 < end; e += 8) {
        int s0 = ssrc[e],     s1 = ssrc[e + 1], s2 = ssrc[e + 2], s3 = ssrc[e + 3];
        int s4 = ssrc[e + 4], s5 = ssrc[e + 5], s6 = ssrc[e + 6], s7 = ssrc[e + 7];
        float d0 = 0.f, d1 = 0.f, d2 = 0.f, d3 = 0.f, d4 = 0.f, d5 = 0.f, d6 = 0.f, d7 = 0.f;
        if (GS) { d0 = dv[s0]; d1 = dv[s1]; d2 = dv[s2]; d3 = dv[s3];
                  d4 = dv[s4]; d5 = dv[s5]; d6 = dv[s6]; d7 = dv[s7]; }
        uint4 v0 = hp[(size_t)s0 * 16 + l];
        uint4 v1 = hp[(size_t)s1 * 16 + l];
        uint4 v2 = hp[(size_t)s2 * 16 + l];
        uint4 v3 = hp[(size_t)s3 * 16 + l];
        uint4 v4 = hp[(size_t)s4 * 16 + l];
        uint4 v5 = hp[(size_t)s5 * 16 + l];
        uint4 v6 = hp[(size_t)s6 * 16 + l];
        uint4 v7 = hp[(size_t)s7 * 16 + l];
        if (GS) { ACC8S(v0, d0); ACC8S(v1, d1); ACC8S(v2, d2); ACC8S(v3, d3);
                  ACC8S(v4, d4); ACC8S(v5, d5); ACC8S(v6, d6); ACC8S(v7, d7); }
        else    { ACC8(v0); ACC8(v1); ACC8(v2); ACC8(v3);
                  ACC8(v4); ACC8(v5); ACC8(v6); ACC8(v7); }
    }
    for (; e + 1 < end; e += 2) {
        int s0 = ssrc[e], s1 = ssrc[e + 1];
        float d0 = 0.f, d1 = 0.f;
        if (GS) { d0 = dv[s0]; d1 = dv[s1]; }
        uint4 v0 = hp[(size_t)s0 * 16 + l];
        uint4 v1 = hp[(size_t)s1 * 16 + l];
        if (GS) { ACC8S(v0, d0); ACC8S(v1, d1); }
        else    { ACC8(v0); ACC8(v1); }
    }
    if (e < end) {
        int s = ssrc[e];
        float d0 = 0.f;
        if (GS) d0 = dv[s];
        uint4 v1 = hp[(size_t)s * 16 + l];
        if (GS) ACC8S(v1, d0); else ACC8(v1);
    }
}

__device__ __forceinline__ void stage_w(const ushort* __restrict__ WT, ushort* sW) {
    int t = threadIdx.x;
#pragma unroll
    for (int j = 0; j < 4; ++j) {
        int idx = t + j * 512;
        int r = idx >> 4, c = idx & 15;
        uint4 v = *(const uint4*)(WT + (size_t)r * 128 + c * 8);
        *(uint4*)(sW + r * 128 + ((c + r) & 15) * 8) = v;
    }
}

template<int MODE>
__device__ __forceinline__ void layer_tile(int tile, const ushort* __restrict__ g,
                                           const float* __restrict__ bias,
                                           const float* __restrict__ dinv,
                                           const int* __restrict__ csr,
                                           const int* __restrict__ ssrc,
                                           ushort* __restrict__ out,
                                           ushort* sW, ushort* sA) {
    int t = threadIdx.x;
    int m0blk = tile * 128;
    int wv   = t >> 6;
    int lane = t & 63;
    int q    = lane >> 4;
    int l    = lane & 15;
    int mw   = m0blk + wv * 16;
    ushort* sAw = sA + wv * (16 * 128);
    const uint4* hp = (const uint4*)g;

    // ---- phase 1: aggregate 4 nodes per quarter-wave into sA (8-deep) ----
#pragma unroll 1
    for (int i = 0; i < 4; ++i) {
        int row  = q * 4 + i;
        int node = mw + row;
        float acc[8];
#pragma unroll
        for (int z = 0; z < 8; ++z) acc[z] = 0.f;
        if (node < N_NODES) {
            uint4 v = hp[(size_t)node * 16 + l];
            if (MODE & 2) { float ds = dinv[node]; ACC8S(v, ds); }
            else          { ACC8(v); }
            int e = csr[node], end = csr[node + 1];
            gather_edges<(MODE & 2) != 0>(hp, ssrc, dinv, e, end, l, acc);
            float d = dinv[node];
#pragma unroll
            for (int z = 0; z < 8; ++z) acc[z] *= d;
        }
        uint4 ov;
        ov.x = (uint)f2bf(acc[0]) | ((uint)f2bf(acc[1]) << 16);
        ov.y = (uint)f2bf(acc[2]) | ((uint)f2bf(acc[3]) << 16);
        ov.z = (uint)f2bf(acc[4]) | ((uint)f2bf(acc[5]) << 16);
        ov.w = (uint)f2bf(acc[6]) | ((uint)f2bf(acc[7]) << 16);
        *(uint4*)(sAw + row * 128 + ((l + row) & 15) * 8) = ov;
    }

    // ---- phase 2: wave-local MFMA ----
    f32x4 facc[8];
#pragma unroll
    for (int n = 0; n < 8; ++n) facc[n] = (f32x4){0.f, 0.f, 0.f, 0.f};
#pragma unroll
    for (int ki = 0; ki < 4; ++ki) {
        int ca = ki * 4 + q;
        bf16x8 a = *(const bf16x8*)(sAw + l * 128 + ((ca + l) & 15) * 8);
#pragma unroll
        for (int n = 0; n < 8; ++n) {
            int rB = n * 16 + l;
            bf16x8 b = *(const bf16x8*)(sW + rB * 128 + ((ca + rB) & 15) * 8);
            facc[n] = __builtin_amdgcn_mfma_f32_16x16x32_bf16(a, b, facc[n], 0, 0, 0);
        }
    }

    // ---- epilogue: restage into sAw ----
    {
        int lr0 = q * 4;
        float sc[4];
#pragma unroll
        for (int r = 0; r < 4; ++r) {
            int m = mw + lr0 + r;
            sc[r] = ((MODE & 1) && m < N_NODES) ? dinv[m] : 1.0f;
        }
#pragma unroll
        for (int n = 0; n < 8; ++n) {
            int col = n * 16 + l;
            float bv = bias[col];
            int c = col >> 3;
#pragma unroll
            for (int r = 0; r < 4; ++r) {
                int lr = lr0 + r;
                float v = facc[n][r] + bv;
                if (MODE & 1) v = fmaxf(v, 0.f) * sc[r];
                sAw[lr * 128 + ((c + lr) & 15) * 8 + (col & 7)] = f2bf(v);
            }
        }
    }
    // ---- coalesced flush (wave-local rows; no barrier needed) ----
#pragma unroll
    for (int j = 0; j < 4; ++j) {
        int idx = lane + j * 64;
        int lr = idx >> 4, c = idx & 15;
        int m = mw + lr;
        if (m < N_NODES) {
            uint4 v = *(const uint4*)(sAw + lr * 128 + ((c + lr) & 15) * 8);
            *(uint4*)(out + (size_t)m * 128 + c * 8) = v;
        }
    }
}

// ---------------- the megakernel: everything, one dispatch ----------------
__global__ __launch_bounds__(512, 4) void mega_kernel(
    const int* __restrict__ row, const int* __restrict__ col,
    const float* __restrict__ x, const int* __restrict__ batch,
    const float* __restrict__ Ws, const float* __restrict__ bs,
    const float* __restrict__ w1, const float* __restrict__ b1,
    const float* __restrict__ w2, const float* __restrict__ b2,
    int* __restrict__ ctrl, unsigned* __restrict__ tmp,
    int* __restrict__ csr, float* __restrict__ dinv, int* __restrict__ ssrc,
    ushort* __restrict__ xb, ushort* __restrict__ hbA, ushort* __restrict__ hbB,
    ushort* __restrict__ WT, int* __restrict__ gstart, float* __restrict__ outp)
{
    __shared__ __align__(16) char smem[65536];   // 64KB static -> 2 blocks/CU
    int* cnt   = ctrl;
    int* bfill = ctrl + 1;                        // NBUCK counts, memset 0
    int t   = threadIdx.x;
    int bid = blockIdx.x;

    // ================= P0: bin + x-convert + WT-convert =================
    {
        unsigned* s_val  = (unsigned*)smem;              // 16KB
        int*      s_dst  = (int*)(smem + 16384);         // 16KB
        int*      s_hist = (int*)(smem + 32768);
        int*      s_scan = (int*)(smem + 33792);
        int*      s_excl = (int*)(smem + 34816);
        int*      s_base = (int*)(smem + 35840);
        int*      s_cur  = (int*)(smem + 36864);
        for (int w = bid; w < NT0; w += GRID) {
            if (w < NT_BIN) {
                int e0 = w * NB_CHUNK;
                if (t < 256) s_hist[t] = 0;
                __syncthreads();
#pragma unroll
                for (int k = 0; k < 8; ++k) {
                    int e = e0 + t + k * 512;
                    if (e < N_EDGES) atomicAdd(&s_hist[col[e] >> 9], 1);
                }
                __syncthreads();
                int h = 0;
                if (t < 256) { h = s_hist[t]; s_scan[t] = h; }
                __syncthreads();
                for (int o = 1; o < 256; o <<= 1) {
                    int u = 0;
                    if (t < 256 && t >= o) u = s_scan[t - o];
                    __syncthreads();
                    if (t < 256) s_scan[t] += u;
                    __syncthreads();
                }
                if (t < NBUCK) {
                    int ex = s_scan[t] - h;
                    s_excl[t] = ex;
                    s_cur[t]  = ex;
                    s_base[t] = atomicAdd(&bfill[t], h);   // old count
                }
                __syncthreads();
#pragma unroll
                for (int k = 0; k < 8; ++k) {
                    int e = e0 + t + k * 512;
                    if (e < N_EDGES) {
                        int r = row[e], c = col[e];
                        int b = c >> 9;
                        int p = atomicAdd(&s_cur[b], 1);
                        int dst = b * CAP + s_base[b] + (p - s_excl[b]);
                        int lim = (b + 1) * CAP;
                        if (dst >= lim) dst = lim - 1;  // overflow clamp
                        s_val[p] = ((unsigned)(c & (BW - 1)) << 17) | (unsigned)r;
                        s_dst[p] = dst;
                    }
                }
                __syncthreads();
                int sc = N_EDGES - e0; if (sc > NB_CHUNK) sc = NB_CHUNK;
#pragma unroll
                for (int k = 0; k < 8; ++k) {
                    int j = t + k * 512;
                    if (j < sc) tmp[s_dst[j]] = s_val[j];
                }
                __syncthreads();
            } else if (w < NT_BIN + NT_CVT) {
                int idx = (w - NT_BIN) * 512 + t;
                int i = idx * 4;
                float4 v = *(const float4*)(x + i);
                ushort4 o;
                o.x = f2bf(v.x); o.y = f2bf(v.y); o.z = f2bf(v.z); o.w = f2bf(v.w);
                *(ushort4*)(xb + i) = o;
                if (idx < N_NODES) {
                    int b  = batch[idx];
                    int bp = (idx == 0) ? -1 : batch[idx - 1];
                    for (int g2 = bp + 1; g2 <= b; ++g2) gstart[g2] = idx;
                    if (idx == N_NODES - 1)
                        for (int g2 = b + 1; g2 <= N_GRAPHS; ++g2) gstart[g2] = N_NODES;
                }
            } else {
                int idx = (w - NT_BIN - NT_CVT) * 512 + t;
                int L = idx >> 14, n = (idx >> 7) & 127, k = idx & 127;
                WT[idx] = f2bf(Ws[(L << 14) + (k << 7) + n]);
            }
        }
    }
    gsync(cnt, GRID * 1);

    // ================= P1: per-bucket sort -> csr/dinv/ssrc =================
    {
        int* t_stage = (int*)smem;                 // 48KB
        int* t_cnt   = (int*)(smem + 49152);       // 2KB
        int* t_pair  = (int*)(smem + 51200);       // 1KB
        int* t_off   = (int*)(smem + 52224);       // 2KB
        int* t_cur   = (int*)(smem + 54272);       // 2KB
        int* t_bb    = (int*)(smem + 56320);       // 1KB
        for (int b = bid; b < NBUCK; b += GRID) {  // <=1 per block
            int wbeg = b * BW;
            int wn = N_NODES - wbeg; if (wn > BW) wn = BW;
            int nE = bfill[b]; if (nE > CAP) nE = CAP;
            const unsigned* T = tmp + (size_t)b * CAP;
            if (b == 0 && t == 0) csr[N_NODES] = N_EDGES;

            if (t < 256) {
                int c0 = 0;
                if (t < NBUCK) { c0 = bfill[t]; if (c0 > CAP) c0 = CAP; }
                t_bb[t] = c0;
            }
            __syncthreads();
            for (int o = 1; o < 256; o <<= 1) {
                int u = 0;
                if (t < 256 && t >= o) u = t_bb[t - o];
                __syncthreads();
                if (t < 256) t_bb[t] += u;
                __syncthreads();
            }
            int base = t_bb[b] - nE;

            for (int i = t; i < BW; i += 512) t_cnt[i] = 0;
            __syncthreads();
            for (int i = t; i < nE; i += 512) atomicAdd(&t_cnt[T[i] >> 17], 1);
            __syncthreads();
            int a0 = 0, a1 = 0;
            if (t < 256) { a0 = t_cnt[2 * t]; a1 = t_cnt[2 * t + 1]; t_pair[t] = a0 + a1; }
            __syncthreads();
            for (int o = 1; o < 256; o <<= 1) {
                int u = 0;
                if (t < 256 && t >= o) u = t_pair[t - o];
                __syncthreads();
                if (t < 256) t_pair[t] += u;
                __syncthreads();
            }
            if (t < 256) {
                int pre = t_pair[t] - (a0 + a1);
                t_off[2 * t] = pre;      t_off[2 * t + 1] = pre + a0;
                t_cur[2 * t] = pre;      t_cur[2 * t + 1] = pre + a0;
            }
            __syncthreads();
            for (int i = t; i < wn; i += 512) {
                csr[wbeg + i]  = base + t_off[i];
                dinv[wbeg + i] = rsqrtf((float)(t_cnt[i] + 1));  // +1 self loop
            }
            for (int i = t; i < nE; i += 512) {
                unsigned v = T[i];
                int p2 = atomicAdd(&t_cur[v >> 17], 1);
                t_stage[p2] = (int)(v & 0x1FFFFu);
            }
            __syncthreads();
            for (int i = t; i < nE; i += 512) ssrc[base + i] = t_stage[i];
        }
    }
    gsync(cnt, GRID * 2);

    // ================= L1..L4 =================
    ushort* sW = (ushort*)smem;
    ushort* sA = (ushort*)(smem + 32768);

    stage_w(WT, sW);
    __syncthreads();
    for (int tile = bid; tile < NT_L; tile += GRID)
        layer_tile<3>(tile, xb, bs, dinv, csr, ssrc, hbA, sW, sA);
    gsync(cnt, GRID * 3);

    stage_w(WT + 16384, sW);
    __syncthreads();
    for (int tile = bid; tile < NT_L; tile += GRID)
        layer_tile<1>(tile, hbA, bs + 128, dinv, csr, ssrc, hbB, sW, sA);
    gsync(cnt, GRID * 4);

    stage_w(WT + 32768, sW);
    __syncthreads();
    for (int tile = bid; tile < NT_L; tile += GRID)
        layer_tile<1>(tile, hbB, bs + 256, dinv, csr, ssrc, hbA, sW, sA);
    gsync(cnt, GRID * 5);

    stage_w(WT + 49152, sW);
    __syncthreads();
    for (int tile = bid; tile < NT_L; tile += GRID)
        layer_tile<0>(tile, hbA, bs + 384, dinv, csr, ssrc, hbB, sW, sA);
    gsync(cnt, GRID * 6);

    // ================= P6: pool + MLP head (1 graph per block) =================
    {
        float* part = (float*)smem;            // 8 x 128
        float* mean = (float*)(smem + 4096);
        float* hid  = (float*)(smem + 4608);
        int g = bid;                            // GRID == N_GRAPHS
        int s = gstart[g], e2 = gstart[g + 1];
        int p = t & 63, which = t >> 6;         // 8 partials
        const uint* hu = (const uint*)hbB;
        float a0 = 0.f, a1 = 0.f;
        for (int n = s + which; n < e2; n += 8) {
            uint v = hu[(size_t)n * 64 + p];
            a0 += bf2f_lo(v);
            a1 += bf2f_hi(v);
        }
        part[which * 128 + 2 * p]     = a0;
        part[which * 128 + 2 * p + 1] = a1;
        __syncthreads();
        if (which == 0) {
            float c = fmaxf((float)(e2 - s), 1.0f);
            float u0 = 0.f, u1 = 0.f;
#pragma unroll
            for (int k = 0; k < 8; ++k) {
                u0 += part[k * 128 + 2 * p];
                u1 += part[k * 128 + 2 * p + 1];
            }
            mean[2 * p]     = u0 / c;
            mean[2 * p + 1] = u1 / c;
        }
        __syncthreads();
        if (t < 100) {
            float s1 = b1[t];
            for (int k = 0; k < 128; ++k) s1 = fmaf(mean[k], w1[k * 100 + t], s1);
            hid[t] = fmaxf(s1, 0.f);
        }
        __syncthreads();
        if (t < 4) {
            float s2 = b2[t];
            for (int j = 0; j < 100; ++j) s2 = fmaf(hid[j], w2[j * 4 + t], s2);
            outp[(size_t)g * 4 + t] = s2;
        }
    }
}

// ---------------- launch: 1 memset + 1 kernel ----------------

extern "C" void kernel_launch(void* const* d_in, const int* in_sizes, int n_in,
                              void* d_out, int out_size, void* d_ws, size_t ws_size,
                              hipStream_t stream) {
    const float* x   = (const float*)d_in[0];
    const float* Ws  = (const float*)d_in[1];
    const float* bs  = (const float*)d_in[2];
    const float* w1  = (const float*)d_in[3];
    const float* b1  = (const float*)d_in[4];
    const float* w2  = (const float*)d_in[5];
    const float* b2  = (const float*)d_in[6];
    const int*   ei  = (const int*)d_in[7];
    const int*   bat = (const int*)d_in[8];
    float* outp = (float*)d_out;

    char* p = (char*)d_ws;
    auto take = [&](size_t bytes) -> void* {
        void* r = (void*)p;
        p += (bytes + 255) & ~(size_t)255;
        return r;
    };
    int*      csr    = (int*)take((size_t)(N_NODES + 1) * 4);
    float*    dinv   = (float*)take((size_t)N_NODES * 4);
    int*      ctrl   = (int*)take((size_t)(1 + NBUCK) * 4);   // [0]=sync cnt, [1..]=bfill
    unsigned* tmp    = (unsigned*)take((size_t)NBUCK * CAP * 4);
    int*      ssrc   = (int*)take((size_t)N_EDGES * 4);
    ushort*   xb     = (ushort*)take((size_t)N_NODES * 128 * 2);
    ushort*   hbA    = (ushort*)take((size_t)N_NODES * 128 * 2);
    ushort*   hbB    = (ushort*)take((size_t)N_NODES * 128 * 2);
    ushort*   WT     = (ushort*)take((size_t)4 * 128 * 128 * 2);
    int*      gstart = (int*)take((size_t)(N_GRAPHS + 1) * 4);

    const int* row = ei;
    const int* col = ei + N_EDGES;

    hipMemsetAsync(ctrl, 0, (size_t)(1 + NBUCK) * 4, stream);
    mega_kernel<<<GRID, NTHR, 0, stream>>>(row, col, x, bat, Ws, bs, w1, b1, w2, b2,
                                           ctrl, tmp, csr, dinv, ssrc,
                                           xb, hbA, hbB, WT, gstart, outp);
}

// Round 6
// 457.751 us; speedup vs baseline: 1.8253x; 1.8253x over previous
//
#include <hip/hip_runtime.h>

#define N_NODES  100000
#define N_EDGES  1600000
#define DIM      128
#define N_GRAPHS 512

#define BW       512                         // nodes per bucket
#define NBUCK    ((N_NODES + BW - 1) / BW)   // 196
#define CAP      12288                       // max edges per bucket (avg 8163, +45 sigma)
#define NB_CHUNK 4096

#define FB_BIN   ((N_EDGES + NB_CHUNK - 1) / NB_CHUNK)   // 391
#define FB_CVT   3125                                     // 12.8M elems / (1024*4)
#define FB_WT    64                                       // 65536 / 1024

typedef short  bf16x8 __attribute__((ext_vector_type(8)));
typedef float  f32x4  __attribute__((ext_vector_type(4)));

__device__ inline ushort f2bf(float f) {  // round-to-nearest-even
    union { float f; unsigned u; } v; v.f = f;
    unsigned r = v.u + 0x7FFFu + ((v.u >> 16) & 1u);
    return (ushort)(r >> 16);
}
__device__ inline float bf2f_lo(unsigned u) { union { unsigned u; float f; } v; v.u = u << 16; return v.f; }
__device__ inline float bf2f_hi(unsigned u) { union { unsigned u; float f; } v; v.u = u & 0xFFFF0000u; return v.f; }

// ---------------- fat front: bin + x-convert + WT-convert (independent) ------
// blocks [0,391): edge binning; [391,3516): x f32->bf16 UNSCALED + gstart;
// [3516,3580): WT[L][n][k] = Ws[L][k][n]. No cross-dependencies -> one launch,
// cvt's ~13us hides under bin. bfill is pure COUNTS (memset-0 before launch).
__global__ __launch_bounds__(1024) void front_kernel(const int* __restrict__ row,
                                                     const int* __restrict__ col,
                                                     int* __restrict__ bfill,
                                                     unsigned* __restrict__ tmp,
                                                     const float* __restrict__ x,
                                                     ushort* __restrict__ xb,
                                                     const int* __restrict__ batch,
                                                     int* __restrict__ gstart,
                                                     const float* __restrict__ Ws,
                                                     ushort* __restrict__ WT) {
    __shared__ unsigned s_val[NB_CHUNK];
    __shared__ int s_dst[NB_CHUNK];
    __shared__ int s_hist[256], s_scan[256];
    __shared__ int s_excl[NBUCK], s_base[NBUCK], s_cur[NBUCK];
    int t = threadIdx.x;
    int bk = blockIdx.x;

    if (bk < FB_BIN) {
        int e0 = bk * NB_CHUNK;
        if (t < 256) s_hist[t] = 0;
        __syncthreads();
#pragma unroll
        for (int k = 0; k < 4; ++k) {
            int e = e0 + t + k * 1024;
            if (e < N_EDGES) atomicAdd(&s_hist[col[e] >> 9], 1);
        }
        __syncthreads();
        int h = 0;
        if (t < 256) { h = s_hist[t]; s_scan[t] = h; }
        __syncthreads();
        for (int o = 1; o < 256; o <<= 1) {
            int u = 0;
            if (t < 256 && t >= o) u = s_scan[t - o];
            __syncthreads();
            if (t < 256) s_scan[t] += u;
            __syncthreads();
        }
        if (t < NBUCK) {
            int ex = s_scan[t] - h;
            s_excl[t] = ex;
            s_cur[t]  = ex;
            s_base[t] = atomicAdd(&bfill[t], h);   // old COUNT for this bucket
        }
        __syncthreads();
#pragma unroll
        for (int k = 0; k < 4; ++k) {
            int e = e0 + t + k * 1024;
            if (e < N_EDGES) {
                int r = row[e], c = col[e];
                int b = c >> 9;
                int p = atomicAdd(&s_cur[b], 1);
                int dst = b * CAP + s_base[b] + (p - s_excl[b]);
                int lim = (b + 1) * CAP;
                if (dst >= lim) dst = lim - 1;  // overflow clamp (statistically impossible)
                s_val[p] = ((unsigned)(c & (BW - 1)) << 17) | (unsigned)r;
                s_dst[p] = dst;
            }
        }
        __syncthreads();
        int sc = N_EDGES - e0; if (sc > NB_CHUNK) sc = NB_CHUNK;
#pragma unroll
        for (int k = 0; k < 4; ++k) {
            int j = t + k * 1024;
            if (j < sc) tmp[s_dst[j]] = s_val[j];
        }
    } else if (bk < FB_BIN + FB_CVT) {
        int idx = (bk - FB_BIN) * 1024 + t;      // 3.2M threads, exact
        int i = idx * 4;
        float4 v = *(const float4*)(x + i);
        ushort4 o;
        o.x = f2bf(v.x); o.y = f2bf(v.y); o.z = f2bf(v.z); o.w = f2bf(v.w);
        *(ushort4*)(xb + i) = o;
        int n = idx;                              // fused bounds_kernel
        if (n < N_NODES) {
            int b  = batch[n];
            int bp = (n == 0) ? -1 : batch[n - 1];
            for (int g = bp + 1; g <= b; ++g) gstart[g] = n;
            if (n == N_NODES - 1) {
                for (int g = b + 1; g <= N_GRAPHS; ++g) gstart[g] = N_NODES;
            }
        }
    } else {
        int idx = (bk - FB_BIN - FB_CVT) * 1024 + t;  // 65536
        int L = idx >> 14, n = (idx >> 7) & 127, k = idx & 127;
        WT[idx] = f2bf(Ws[(L << 14) + (k << 7) + n]);
    }
}

// 1024 threads: count/scatter/flush; pair-scan on t<256. bscan inlined
// (196-elem scan of clamped counts). bfill holds COUNTS. block 0 sets csr[N].
__global__ __launch_bounds__(1024) void sort_kernel(const unsigned* __restrict__ tmp,
                                                    const int* __restrict__ bfill,
                                                    int* __restrict__ csr,
                                                    float* __restrict__ dinv,
                                                    int* __restrict__ ssrc) {
    __shared__ int s_cnt[BW];
    __shared__ int s_pair[256];
    __shared__ int s_off[BW];
    __shared__ int s_cur[BW];
    __shared__ int s_bb[256];
    __shared__ int s_stage[CAP];
    int b = blockIdx.x, t = threadIdx.x;
    int wbeg = b * BW;
    int wn = N_NODES - wbeg; if (wn > BW) wn = BW;
    int nE = bfill[b]; if (nE > CAP) nE = CAP;
    const unsigned* T = tmp + (size_t)b * CAP;

    if (b == 0 && t == 0) csr[N_NODES] = N_EDGES;

    // ---- inline bscan: inclusive prefix of clamped bucket counts ----
    if (t < 256) {
        int c0 = 0;
        if (t < NBUCK) {
            c0 = bfill[t];
            if (c0 > CAP) c0 = CAP;
        }
        s_bb[t] = c0;
    }
    __syncthreads();
    for (int o = 1; o < 256; o <<= 1) {
        int u = 0;
        if (t < 256 && t >= o) u = s_bb[t - o];
        __syncthreads();
        if (t < 256) s_bb[t] += u;
        __syncthreads();
    }
    int base = s_bb[b] - nE;   // exclusive prefix for this bucket

    for (int i = t; i < BW; i += 1024) s_cnt[i] = 0;
    __syncthreads();
    for (int i = t; i < nE; i += 1024) atomicAdd(&s_cnt[T[i] >> 17], 1);
    __syncthreads();
    int a0 = 0, a1 = 0;
    if (t < 256) { a0 = s_cnt[2 * t]; a1 = s_cnt[2 * t + 1]; s_pair[t] = a0 + a1; }
    __syncthreads();
    for (int o = 1; o < 256; o <<= 1) {
        int u = 0;
        if (t < 256 && t >= o) u = s_pair[t - o];
        __syncthreads();
        if (t < 256) s_pair[t] += u;
        __syncthreads();
    }
    if (t < 256) {
        int pre = s_pair[t] - (a0 + a1);
        s_off[2 * t] = pre;      s_off[2 * t + 1] = pre + a0;
        s_cur[2 * t] = pre;      s_cur[2 * t + 1] = pre + a0;
    }
    __syncthreads();
    for (int i = t; i < wn; i += 1024) {
        csr[wbeg + i]  = base + s_off[i];
        dinv[wbeg + i] = rsqrtf((float)(s_cnt[i] + 1));  // +1 = self loop
    }
    for (int i = t; i < nE; i += 1024) {
        unsigned v = T[i];
        int p = atomicAdd(&s_cur[v >> 17], 1);
        s_stage[p] = (int)(v & 0x1FFFFu);
    }
    __syncthreads();
    for (int i = t; i < nE; i += 1024) ssrc[base + i] = s_stage[i];
}

// ---------------- fused layer: aggregate (to LDS) + MFMA GEMM ----------------
// mode bits: 1 = relu + dinv-prescale epilogue (layers 1-3); 2 = scale-by-
// dinv[src] during gather (layer 1, xb unscaled). All layers flush h via the
// coalesced global write (R4 lesson: writes are free under the fetch-bound
// gather; atomic pooling cost +14us — removed). Gather sits at the
// compulsory-fetch line-rate floor (~191 MB @ 2.8-2.9 TB/s, 4x confirmed).
// in/out MUST be distinct (ping-pong).
#define ACC8(vv) do { \
    acc[0] += bf2f_lo((vv).x); acc[1] += bf2f_hi((vv).x); \
    acc[2] += bf2f_lo((vv).y); acc[3] += bf2f_hi((vv).y); \
    acc[4] += bf2f_lo((vv).z); acc[5] += bf2f_hi((vv).z); \
    acc[6] += bf2f_lo((vv).w); acc[7] += bf2f_hi((vv).w); } while (0)

#define ACC8S(vv, dd) do { \
    acc[0] = fmaf(bf2f_lo((vv).x), dd, acc[0]); acc[1] = fmaf(bf2f_hi((vv).x), dd, acc[1]); \
    acc[2] = fmaf(bf2f_lo((vv).y), dd, acc[2]); acc[3] = fmaf(bf2f_hi((vv).y), dd, acc[3]); \
    acc[4] = fmaf(bf2f_lo((vv).z), dd, acc[4]); acc[5] = fmaf(bf2f_hi((vv).z), dd, acc[5]); \
    acc[6] = fmaf(bf2f_lo((vv).w), dd, acc[6]); acc[7] = fmaf(bf2f_hi((vv).w), dd, acc[7]); } while (0)

template<bool GS>
__device__ __forceinline__ void gather_edges(const uint4* __restrict__ hp,
                                             const int* __restrict__ ssrc,
                                             const float* __restrict__ dv,
                                             int e, int end, int l, float* acc) {
    for (; e + 7 < end; e += 8) {
        int s0 = ssrc[e],     s1 = ssrc[e + 1], s2 = ssrc[e + 2], s3 = ssrc[e + 3];
        int s4 = ssrc[e + 4], s5 = ssrc[e + 5], s6 = ssrc[e + 6], s7 = ssrc[e + 7];
        float d0 = 0.f, d1 = 0.f, d2 = 0.f, d3 = 0.f, d4 = 0.f, d5 = 0.f, d6 = 0.f, d7 = 0.f;
        if (GS) { d0 = dv[s0]; d1 = dv[s1]; d2 = dv[s2]; d3 = dv[s3];
                  d4 = dv[s4]; d5 = dv[s5]; d6 = dv[s6]; d7 = dv[s7]; }
        uint4 v0 = hp[(size_t)s0 * 16 + l];
        uint4 v1 = hp[(size_t)s1 * 16 + l];
        uint4 v2 = hp[(size_t)s2 * 16 + l];
        uint4 v3 = hp[(size_t)s3 * 16 + l];
        uint4 v4 = hp[(size_t)s4 * 16 + l];
        uint4 v5 = hp[(size_t)s5 * 16 + l];
        uint4 v6 = hp[(size_t)s6 * 16 + l];
        uint4 v7 = hp[(size_t)s7 * 16 + l];
        if (GS) { ACC8S(v0, d0); ACC8S(v1, d1); ACC8S(v2, d2); ACC8S(v3, d3);
                  ACC8S(v4, d4); ACC8S(v5, d5); ACC8S(v6, d6); ACC8S(v7, d7); }
        else    { ACC8(v0); ACC8(v1); ACC8(v2); ACC8(v3);
                  ACC8(v4); ACC8(v5); ACC8(v6); ACC8(v7); }
    }
    for (; e + 1 < end; e += 2) {
        int s0 = ssrc[e], s1 = ssrc[e + 1];
        float d0 = 0.f, d1 = 0.f;
        if (GS) { d0 = dv[s0]; d1 = dv[s1]; }
        uint4 v0 = hp[(size_t)s0 * 16 + l];
        uint4 v1 = hp[(size_t)s1 * 16 + l];
        if (GS) { ACC8S(v0, d0); ACC8S(v1, d1); }
        else    { ACC8(v0); ACC8(v1); }
    }
    if (e < end) {
        int s = ssrc[e];
        float d0 = 0.f;
        if (GS) d0 = dv[s];
        uint4 v1 = hp[(size_t)s * 16 + l];
        if (GS) ACC8S(v1, d0); else ACC8(v1);
    }
}

__global__ __launch_bounds__(512) void layer_kernel(const ushort* __restrict__ g,
                                                    const ushort* __restrict__ WT,
                                                    const float* __restrict__ bias,
                                                    const float* __restrict__ dinv,
                                                    const int* __restrict__ csr,
                                                    const int* __restrict__ ssrc,
                                                    ushort* __restrict__ out,
                                                    int mode) {
    __shared__ ushort sW[128 * 128];        // swizzled
    __shared__ ushort sA[8][16 * 128];      // per-wave, swizzled
    int t = threadIdx.x;
    int m0blk = blockIdx.x * 128;

    {   // stage WT swizzled: 2048 uint4, 4 per thread
#pragma unroll
        for (int j = 0; j < 4; ++j) {
            int idx = t + j * 512;
            int r = idx >> 4, c = idx & 15;
            uint4 v = *(const uint4*)(WT + (size_t)r * 128 + c * 8);
            *(uint4*)(sW + r * 128 + ((c + r) & 15) * 8) = v;
        }
    }
    __syncthreads();

    int wv   = t >> 6;
    int lane = t & 63;
    int q    = lane >> 4;
    int l    = lane & 15;
    int mw   = m0blk + wv * 16;
    ushort* sAw = sA[wv];
    const uint4* hp = (const uint4*)g;

    // ---- phase 1: aggregate 4 nodes per quarter-wave into sA (8-deep) ----
#pragma unroll 1
    for (int i = 0; i < 4; ++i) {
        int row  = q * 4 + i;
        int node = mw + row;
        float acc[8];
#pragma unroll
        for (int z = 0; z < 8; ++z) acc[z] = 0.f;
        if (node < N_NODES) {
            uint4 v = hp[(size_t)node * 16 + l];
            if (mode & 2) { float ds = dinv[node]; ACC8S(v, ds); }
            else          { ACC8(v); }
            int e = csr[node], end = csr[node + 1];
            if (mode & 2) gather_edges<true>(hp, ssrc, dinv, e, end, l, acc);
            else          gather_edges<false>(hp, ssrc, dinv, e, end, l, acc);
            float d = dinv[node];
#pragma unroll
            for (int z = 0; z < 8; ++z) acc[z] *= d;
        }
        uint4 ov;
        ov.x = (uint)f2bf(acc[0]) | ((uint)f2bf(acc[1]) << 16);
        ov.y = (uint)f2bf(acc[2]) | ((uint)f2bf(acc[3]) << 16);
        ov.z = (uint)f2bf(acc[4]) | ((uint)f2bf(acc[5]) << 16);
        ov.w = (uint)f2bf(acc[6]) | ((uint)f2bf(acc[7]) << 16);
        *(uint4*)(sAw + row * 128 + ((l + row) & 15) * 8) = ov;
    }

    // ---- phase 2: wave-local MFMA (A rows = this wave's 16 nodes) ----
    f32x4 facc[8];
#pragma unroll
    for (int n = 0; n < 8; ++n) facc[n] = (f32x4){0.f, 0.f, 0.f, 0.f};
#pragma unroll
    for (int ki = 0; ki < 4; ++ki) {
        int ca = ki * 4 + q;  // A chunk for this lane (row = l)
        bf16x8 a = *(const bf16x8*)(sAw + l * 128 + ((ca + l) & 15) * 8);
#pragma unroll
        for (int n = 0; n < 8; ++n) {
            int rB = n * 16 + l;
            bf16x8 b = *(const bf16x8*)(sW + rB * 128 + ((ca + rB) & 15) * 8);
            facc[n] = __builtin_amdgcn_mfma_f32_16x16x32_bf16(a, b, facc[n], 0, 0, 0);
        }
    }

    // ---- epilogue: restage into sAw, then coalesced flush ----
    {
        int lr0 = q * 4;  // C/D: local row = q*4 + reg, col = n*16 + l
        bool rp = (mode & 1);
        float sc[4];
#pragma unroll
        for (int r = 0; r < 4; ++r) {
            int m = mw + lr0 + r;
            sc[r] = (rp && m < N_NODES) ? dinv[m] : 1.0f;
        }
#pragma unroll
        for (int n = 0; n < 8; ++n) {
            int col = n * 16 + l;
            float bv = bias[col];
            int c = col >> 3;
#pragma unroll
            for (int r = 0; r < 4; ++r) {
                int lr = lr0 + r;
                float v = facc[n][r] + bv;
                if (rp) v = fmaxf(v, 0.f) * sc[r];
                sAw[lr * 128 + ((c + lr) & 15) * 8 + (col & 7)] = f2bf(v);
            }
        }
    }
#pragma unroll
    for (int j = 0; j < 4; ++j) {
        int idx = lane + j * 64;
        int lr = idx >> 4, c = idx & 15;
        int m = mw + lr;
        if (m < N_NODES) {
            uint4 v = *(const uint4*)(sAw + lr * 128 + ((c + lr) & 15) * 8);
            *(uint4*)(out + (size_t)m * 128 + c * 8) = v;
        }
    }
}

// ---------------- fused pooling + MLP head (one block per graph) -------------

__global__ __launch_bounds__(256) void pool_mlp(const ushort* __restrict__ h,
                                                const int* __restrict__ gstart,
                                                const float* __restrict__ w1,
                                                const float* __restrict__ b1,
                                                const float* __restrict__ w2,
                                                const float* __restrict__ b2,
                                                float* __restrict__ out) {
    __shared__ float part[4][128];
    __shared__ float mean[128];
    __shared__ float hid[100];
    int g = blockIdx.x;
    int s = gstart[g], e2 = gstart[g + 1];
    int p     = threadIdx.x & 63;
    int which = threadIdx.x >> 6;
    const uint* hu = (const uint*)h;

    float a0 = 0.f, a1 = 0.f;
    for (int n = s + which; n < e2; n += 4) {
        uint v = hu[(size_t)n * 64 + p];
        a0 += bf2f_lo(v);
        a1 += bf2f_hi(v);
    }
    part[which][2 * p]     = a0;
    part[which][2 * p + 1] = a1;
    __syncthreads();
    if (which == 0) {
        float c = fmaxf((float)(e2 - s), 1.0f);
        mean[2 * p]     = (part[0][2 * p] + part[1][2 * p] + part[2][2 * p] + part[3][2 * p]) / c;
        mean[2 * p + 1] = (part[0][2 * p + 1] + part[1][2 * p + 1] + part[2][2 * p + 1] + part[3][2 * p + 1]) / c;
    }
    __syncthreads();
    int t = threadIdx.x;
    if (t < 100) {
        float s1 = b1[t];
        for (int k = 0; k < 128; ++k) s1 = fmaf(mean[k], w1[k * 100 + t], s1);
        hid[t] = fmaxf(s1, 0.f);
    }
    __syncthreads();
    if (t < 4) {
        float s2 = b2[t];
        for (int j = 0; j < 100; ++j) s2 = fmaf(hid[j], w2[j * 4 + t], s2);
        out[(size_t)g * 4 + t] = s2;
    }
}

// ---------------- launch ----------------

extern "C" void kernel_launch(void* const* d_in, const int* in_sizes, int n_in,
                              void* d_out, int out_size, void* d_ws, size_t ws_size,
                              hipStream_t stream) {
    const float* x   = (const float*)d_in[0];
    const float* Ws  = (const float*)d_in[1];
    const float* bs  = (const float*)d_in[2];
    const float* w1  = (const float*)d_in[3];
    const float* b1  = (const float*)d_in[4];
    const float* w2  = (const float*)d_in[5];
    const float* b2  = (const float*)d_in[6];
    const int*   ei  = (const int*)d_in[7];
    const int*   bat = (const int*)d_in[8];
    float* outp = (float*)d_out;

    char* p = (char*)d_ws;
    auto take = [&](size_t bytes) -> void* {
        void* r = (void*)p;
        p += (bytes + 255) & ~(size_t)255;
        return r;
    };
    int*      csr    = (int*)take((size_t)(N_NODES + 1) * 4);
    float*    dinv   = (float*)take((size_t)N_NODES * 4);
    int*      bfill  = (int*)take((size_t)NBUCK * 4);
    unsigned* tmp    = (unsigned*)take((size_t)NBUCK * CAP * 4);
    int*      ssrc   = (int*)take((size_t)N_EDGES * 4);
    ushort*   xb     = (ushort*)take((size_t)N_NODES * 128 * 2);
    ushort*   hbA    = (ushort*)take((size_t)N_NODES * 128 * 2);
    ushort*   hbB    = (ushort*)take((size_t)N_NODES * 128 * 2);
    ushort*   WT     = (ushort*)take((size_t)4 * 128 * 128 * 2);
    int*      gstart = (int*)take((size_t)(N_GRAPHS + 1) * 4);

    const int* row = ei;
    const int* col = ei + N_EDGES;

    hipMemsetAsync(bfill, 0, (size_t)NBUCK * 4, stream);

    front_kernel<<<FB_BIN + FB_CVT + FB_WT, 1024, 0, stream>>>(
        row, col, bfill, tmp, x, xb, bat, gstart, Ws, WT);
    sort_kernel<<<NBUCK, 1024, 0, stream>>>(tmp, bfill, csr, dinv, ssrc);

    // ping-pong: layer input and output must be DISTINCT buffers (blocks
    // gather from rows other blocks write). L1: gather-scale (xb unscaled).
    const ushort* hin = xb;
    ushort* hout = hbA;
    for (int L = 0; L < 4; ++L) {
        int mode = (L == 0) ? 3 : (L < 3) ? 1 : 0;
        layer_kernel<<<(N_NODES + 127) / 128, 512, 0, stream>>>(
            hin, WT + (size_t)L * 128 * 128, bs + (size_t)L * 128, dinv,
            csr, ssrc, hout, mode);
        hin = hout;
        hout = (hout == hbA) ? hbB : hbA;
    }
    // after 4 layers: hin points at the final output buffer
    pool_mlp<<<N_GRAPHS, 256, 0, stream>>>(hin, gstart, w1, b1, w2, b2, outp);
}

// Round 7
// 452.236 us; speedup vs baseline: 1.8476x; 1.0122x over previous
//
#include <hip/hip_runtime.h>

#define N_NODES  100000
#define N_EDGES  1600000
#define DIM      128
#define N_GRAPHS 512

#define BW       512                         // nodes per bucket
#define NBUCK    ((N_NODES + BW - 1) / BW)   // 196
#define CAP      12288                       // max edges per bucket (avg 8163, +45 sigma)
#define NB_CHUNK 4096

#define FB_BIN   ((N_EDGES + NB_CHUNK - 1) / NB_CHUNK)   // 391
#define FB_WT    64                                       // 65536 / 1024

typedef short  bf16x8 __attribute__((ext_vector_type(8)));
typedef float  f32x4  __attribute__((ext_vector_type(4)));

__device__ inline ushort f2bf(float f) {  // round-to-nearest-even
    union { float f; unsigned u; } v; v.f = f;
    unsigned r = v.u + 0x7FFFu + ((v.u >> 16) & 1u);
    return (ushort)(r >> 16);
}
__device__ inline float bf2f_lo(unsigned u) { union { unsigned u; float f; } v; v.u = u << 16; return v.f; }
__device__ inline float bf2f_hi(unsigned u) { union { unsigned u; float f; } v; v.u = u & 0xFFFF0000u; return v.f; }

// ---------------- front: bin + WT-convert (both sort-independent) ------------
// blocks [0,391): edge binning; [391,455): WT[L][n][k] = Ws[L][k][n] bf16.
// bfill holds pure COUNTS (memset-0 before launch). cvt_x is NOT here: it
// needs dinv (R6 lesson: gather-scale in L1 costs +8us on the fetch-limited
// path — prescaled xb is cheaper, so cvt runs after sort).
__global__ __launch_bounds__(1024) void front_kernel(const int* __restrict__ row,
                                                     const int* __restrict__ col,
                                                     int* __restrict__ bfill,
                                                     unsigned* __restrict__ tmp,
                                                     const float* __restrict__ Ws,
                                                     ushort* __restrict__ WT) {
    __shared__ unsigned s_val[NB_CHUNK];
    __shared__ int s_dst[NB_CHUNK];
    __shared__ int s_hist[256], s_scan[256];
    __shared__ int s_excl[NBUCK], s_base[NBUCK], s_cur[NBUCK];
    int t = threadIdx.x;
    int bk = blockIdx.x;

    if (bk < FB_BIN) {
        int e0 = bk * NB_CHUNK;
        if (t < 256) s_hist[t] = 0;
        __syncthreads();
#pragma unroll
        for (int k = 0; k < 4; ++k) {
            int e = e0 + t + k * 1024;
            if (e < N_EDGES) atomicAdd(&s_hist[col[e] >> 9], 1);
        }
        __syncthreads();
        int h = 0;
        if (t < 256) { h = s_hist[t]; s_scan[t] = h; }
        __syncthreads();
        for (int o = 1; o < 256; o <<= 1) {
            int u = 0;
            if (t < 256 && t >= o) u = s_scan[t - o];
            __syncthreads();
            if (t < 256) s_scan[t] += u;
            __syncthreads();
        }
        if (t < NBUCK) {
            int ex = s_scan[t] - h;
            s_excl[t] = ex;
            s_cur[t]  = ex;
            s_base[t] = atomicAdd(&bfill[t], h);   // old COUNT for this bucket
        }
        __syncthreads();
#pragma unroll
        for (int k = 0; k < 4; ++k) {
            int e = e0 + t + k * 1024;
            if (e < N_EDGES) {
                int r = row[e], c = col[e];
                int b = c >> 9;
                int p = atomicAdd(&s_cur[b], 1);
                int dst = b * CAP + s_base[b] + (p - s_excl[b]);
                int lim = (b + 1) * CAP;
                if (dst >= lim) dst = lim - 1;  // overflow clamp (statistically impossible)
                s_val[p] = ((unsigned)(c & (BW - 1)) << 17) | (unsigned)r;
                s_dst[p] = dst;
            }
        }
        __syncthreads();
        int sc = N_EDGES - e0; if (sc > NB_CHUNK) sc = NB_CHUNK;
#pragma unroll
        for (int k = 0; k < 4; ++k) {
            int j = t + k * 1024;
            if (j < sc) tmp[s_dst[j]] = s_val[j];
        }
    } else {
        int idx = (bk - FB_BIN) * 1024 + t;  // 65536
        int L = idx >> 14, n = (idx >> 7) & 127, k = idx & 127;
        WT[idx] = f2bf(Ws[(L << 14) + (k << 7) + n]);
    }
}

// 1024 threads: count/scatter/flush; pair-scan on t<256. bscan inlined
// (196-elem scan of clamped counts). bfill holds COUNTS. block 0 sets csr[N].
__global__ __launch_bounds__(1024) void sort_kernel(const unsigned* __restrict__ tmp,
                                                    const int* __restrict__ bfill,
                                                    int* __restrict__ csr,
                                                    float* __restrict__ dinv,
                                                    int* __restrict__ ssrc) {
    __shared__ int s_cnt[BW];
    __shared__ int s_pair[256];
    __shared__ int s_off[BW];
    __shared__ int s_cur[BW];
    __shared__ int s_bb[256];
    __shared__ int s_stage[CAP];
    int b = blockIdx.x, t = threadIdx.x;
    int wbeg = b * BW;
    int wn = N_NODES - wbeg; if (wn > BW) wn = BW;
    int nE = bfill[b]; if (nE > CAP) nE = CAP;
    const unsigned* T = tmp + (size_t)b * CAP;

    if (b == 0 && t == 0) csr[N_NODES] = N_EDGES;

    // ---- inline bscan: inclusive prefix of clamped bucket counts ----
    if (t < 256) {
        int c0 = 0;
        if (t < NBUCK) {
            c0 = bfill[t];
            if (c0 > CAP) c0 = CAP;
        }
        s_bb[t] = c0;
    }
    __syncthreads();
    for (int o = 1; o < 256; o <<= 1) {
        int u = 0;
        if (t < 256 && t >= o) u = s_bb[t - o];
        __syncthreads();
        if (t < 256) s_bb[t] += u;
        __syncthreads();
    }
    int base = s_bb[b] - nE;   // exclusive prefix for this bucket

    for (int i = t; i < BW; i += 1024) s_cnt[i] = 0;
    __syncthreads();
    for (int i = t; i < nE; i += 1024) atomicAdd(&s_cnt[T[i] >> 17], 1);
    __syncthreads();
    int a0 = 0, a1 = 0;
    if (t < 256) { a0 = s_cnt[2 * t]; a1 = s_cnt[2 * t + 1]; s_pair[t] = a0 + a1; }
    __syncthreads();
    for (int o = 1; o < 256; o <<= 1) {
        int u = 0;
        if (t < 256 && t >= o) u = s_pair[t - o];
        __syncthreads();
        if (t < 256) s_pair[t] += u;
        __syncthreads();
    }
    if (t < 256) {
        int pre = s_pair[t] - (a0 + a1);
        s_off[2 * t] = pre;      s_off[2 * t + 1] = pre + a0;
        s_cur[2 * t] = pre;      s_cur[2 * t + 1] = pre + a0;
    }
    __syncthreads();
    for (int i = t; i < wn; i += 1024) {
        csr[wbeg + i]  = base + s_off[i];
        dinv[wbeg + i] = rsqrtf((float)(s_cnt[i] + 1));  // +1 = self loop
    }
    for (int i = t; i < nE; i += 1024) {
        unsigned v = T[i];
        int p = atomicAdd(&s_cur[v >> 17], 1);
        s_stage[p] = (int)(v & 0x1FFFFu);
    }
    __syncthreads();
    for (int i = t; i < nE; i += 1024) ssrc[base + i] = s_stage[i];
}

// ---------------- dtype conversion (dinv-prescaled) + graph-bounds -----------

// xb[i] = bf16( x[i] * dinv[node] ) — R3-proven form; also emits gstart
__global__ __launch_bounds__(256) void cvt_x(const float* __restrict__ x,
                                             const float* __restrict__ dinv,
                                             ushort* __restrict__ xb,
                                             const int* __restrict__ batch,
                                             int* __restrict__ gstart) {
    int i = (blockIdx.x * 256 + threadIdx.x) * 4;  // 12.8M elements, exact
    float d = dinv[i >> 7];
    float4 v = *(const float4*)(x + i);
    ushort4 o;
    o.x = f2bf(v.x * d); o.y = f2bf(v.y * d); o.z = f2bf(v.z * d); o.w = f2bf(v.w * d);
    *(ushort4*)(xb + i) = o;

    int n = blockIdx.x * 256 + threadIdx.x;   // fused bounds_kernel
    if (n < N_NODES) {
        int b  = batch[n];
        int bp = (n == 0) ? -1 : batch[n - 1];
        for (int g = bp + 1; g <= b; ++g) gstart[g] = n;
        if (n == N_NODES - 1) {
            for (int g = b + 1; g <= N_GRAPHS; ++g) gstart[g] = N_NODES;
        }
    }
}

// ---------------- fused layer: aggregate (to LDS) + MFMA GEMM ----------------
// R0/R3 form (76.5 us measured; floor). mode 1 = relu + dinv-prescale epilogue
// (layers 1-3); mode 0 = plain (layer 4). Input is always dinv-prescaled.
// Floor evidence: FETCH ~191 MB = compulsory 8-XCD replication of h (every
// 256B row fully consumed; random graph -> no locality), delivered at
// 2.8-2.9 TB/s across 5 different schedules. in/out MUST be distinct.
#define ACC8(vv) do { \
    acc[0] += bf2f_lo((vv).x); acc[1] += bf2f_hi((vv).x); \
    acc[2] += bf2f_lo((vv).y); acc[3] += bf2f_hi((vv).y); \
    acc[4] += bf2f_lo((vv).z); acc[5] += bf2f_hi((vv).z); \
    acc[6] += bf2f_lo((vv).w); acc[7] += bf2f_hi((vv).w); } while (0)

__global__ __launch_bounds__(512) void layer_kernel(const ushort* __restrict__ g,
                                                    const ushort* __restrict__ WT,
                                                    const float* __restrict__ bias,
                                                    const float* __restrict__ dinv,
                                                    const int* __restrict__ csr,
                                                    const int* __restrict__ ssrc,
                                                    ushort* __restrict__ out,
                                                    int mode) {
    __shared__ ushort sW[128 * 128];        // swizzled
    __shared__ ushort sA[8][16 * 128];      // per-wave, swizzled
    int t = threadIdx.x;
    int m0blk = blockIdx.x * 128;

    {   // stage WT swizzled: 2048 uint4, 4 per thread
#pragma unroll
        for (int j = 0; j < 4; ++j) {
            int idx = t + j * 512;
            int r = idx >> 4, c = idx & 15;
            uint4 v = *(const uint4*)(WT + (size_t)r * 128 + c * 8);
            *(uint4*)(sW + r * 128 + ((c + r) & 15) * 8) = v;
        }
    }
    __syncthreads();

    int wv   = t >> 6;
    int lane = t & 63;
    int q    = lane >> 4;
    int l    = lane & 15;
    int mw   = m0blk + wv * 16;
    ushort* sAw = sA[wv];
    const uint4* hp = (const uint4*)g;

    // ---- phase 1: aggregate 4 nodes per quarter-wave into sA (8-deep) ----
#pragma unroll 1
    for (int i = 0; i < 4; ++i) {
        int row  = q * 4 + i;
        int node = mw + row;
        float acc[8];
#pragma unroll
        for (int z = 0; z < 8; ++z) acc[z] = 0.f;
        if (node < N_NODES) {
            uint4 v = hp[(size_t)node * 16 + l];
            acc[0] = bf2f_lo(v.x); acc[1] = bf2f_hi(v.x);
            acc[2] = bf2f_lo(v.y); acc[3] = bf2f_hi(v.y);
            acc[4] = bf2f_lo(v.z); acc[5] = bf2f_hi(v.z);
            acc[6] = bf2f_lo(v.w); acc[7] = bf2f_hi(v.w);
            int e = csr[node], end = csr[node + 1];
            for (; e + 7 < end; e += 8) {
                int s0 = ssrc[e],     s1 = ssrc[e + 1], s2 = ssrc[e + 2], s3 = ssrc[e + 3];
                int s4 = ssrc[e + 4], s5 = ssrc[e + 5], s6 = ssrc[e + 6], s7 = ssrc[e + 7];
                uint4 v0 = hp[(size_t)s0 * 16 + l];
                uint4 v1 = hp[(size_t)s1 * 16 + l];
                uint4 v2 = hp[(size_t)s2 * 16 + l];
                uint4 v3 = hp[(size_t)s3 * 16 + l];
                uint4 v4 = hp[(size_t)s4 * 16 + l];
                uint4 v5 = hp[(size_t)s5 * 16 + l];
                uint4 v6 = hp[(size_t)s6 * 16 + l];
                uint4 v7 = hp[(size_t)s7 * 16 + l];
                ACC8(v0); ACC8(v1); ACC8(v2); ACC8(v3);
                ACC8(v4); ACC8(v5); ACC8(v6); ACC8(v7);
            }
            for (; e + 1 < end; e += 2) {
                int s0 = ssrc[e], s1 = ssrc[e + 1];
                uint4 v0 = hp[(size_t)s0 * 16 + l];
                uint4 v1 = hp[(size_t)s1 * 16 + l];
                ACC8(v0); ACC8(v1);
            }
            if (e < end) {
                int s = ssrc[e];
                uint4 v1 = hp[(size_t)s * 16 + l];
                ACC8(v1);
            }
            float d = dinv[node];
#pragma unroll
            for (int z = 0; z < 8; ++z) acc[z] *= d;
        }
        uint4 ov;
        ov.x = (uint)f2bf(acc[0]) | ((uint)f2bf(acc[1]) << 16);
        ov.y = (uint)f2bf(acc[2]) | ((uint)f2bf(acc[3]) << 16);
        ov.z = (uint)f2bf(acc[4]) | ((uint)f2bf(acc[5]) << 16);
        ov.w = (uint)f2bf(acc[6]) | ((uint)f2bf(acc[7]) << 16);
        *(uint4*)(sAw + row * 128 + ((l + row) & 15) * 8) = ov;
    }

    // ---- phase 2: wave-local MFMA (A rows = this wave's 16 nodes) ----
    f32x4 facc[8];
#pragma unroll
    for (int n = 0; n < 8; ++n) facc[n] = (f32x4){0.f, 0.f, 0.f, 0.f};
#pragma unroll
    for (int ki = 0; ki < 4; ++ki) {
        int ca = ki * 4 + q;  // A chunk for this lane (row = l)
        bf16x8 a = *(const bf16x8*)(sAw + l * 128 + ((ca + l) & 15) * 8);
#pragma unroll
        for (int n = 0; n < 8; ++n) {
            int rB = n * 16 + l;
            bf16x8 b = *(const bf16x8*)(sW + rB * 128 + ((ca + rB) & 15) * 8);
            facc[n] = __builtin_amdgcn_mfma_f32_16x16x32_bf16(a, b, facc[n], 0, 0, 0);
        }
    }

    // ---- epilogue: restage into sAw, then coalesced flush ----
    {
        int lr0 = q * 4;  // C/D: local row = q*4 + reg, col = n*16 + l
        float sc[4];
#pragma unroll
        for (int r = 0; r < 4; ++r) {
            int m = mw + lr0 + r;
            sc[r] = (mode && m < N_NODES) ? dinv[m] : 1.0f;
        }
#pragma unroll
        for (int n = 0; n < 8; ++n) {
            int col = n * 16 + l;
            float bv = bias[col];
            int c = col >> 3;
#pragma unroll
            for (int r = 0; r < 4; ++r) {
                int lr = lr0 + r;
                float v = facc[n][r] + bv;
                if (mode) v = fmaxf(v, 0.f) * sc[r];
                sAw[lr * 128 + ((c + lr) & 15) * 8 + (col & 7)] = f2bf(v);
            }
        }
    }
#pragma unroll
    for (int j = 0; j < 4; ++j) {
        int idx = lane + j * 64;
        int lr = idx >> 4, c = idx & 15;
        int m = mw + lr;
        if (m < N_NODES) {
            uint4 v = *(const uint4*)(sAw + lr * 128 + ((c + lr) & 15) * 8);
            *(uint4*)(out + (size_t)m * 128 + c * 8) = v;
        }
    }
}

// ---------------- fused pooling + MLP head (one block per graph) -------------

__global__ __launch_bounds__(256) void pool_mlp(const ushort* __restrict__ h,
                                                const int* __restrict__ gstart,
                                                const float* __restrict__ w1,
                                                const float* __restrict__ b1,
                                                const float* __restrict__ w2,
                                                const float* __restrict__ b2,
                                                float* __restrict__ out) {
    __shared__ float part[4][128];
    __shared__ float mean[128];
    __shared__ float hid[100];
    int g = blockIdx.x;
    int s = gstart[g], e2 = gstart[g + 1];
    int p     = threadIdx.x & 63;
    int which = threadIdx.x >> 6;
    const uint* hu = (const uint*)h;

    float a0 = 0.f, a1 = 0.f;
    for (int n = s + which; n < e2; n += 4) {
        uint v = hu[(size_t)n * 64 + p];
        a0 += bf2f_lo(v);
        a1 += bf2f_hi(v);
    }
    part[which][2 * p]     = a0;
    part[which][2 * p + 1] = a1;
    __syncthreads();
    if (which == 0) {
        float c = fmaxf((float)(e2 - s), 1.0f);
        mean[2 * p]     = (part[0][2 * p] + part[1][2 * p] + part[2][2 * p] + part[3][2 * p]) / c;
        mean[2 * p + 1] = (part[0][2 * p + 1] + part[1][2 * p + 1] + part[2][2 * p + 1] + part[3][2 * p + 1]) / c;
    }
    __syncthreads();
    int t = threadIdx.x;
    if (t < 100) {
        float s1 = b1[t];
        for (int k = 0; k < 128; ++k) s1 = fmaf(mean[k], w1[k * 100 + t], s1);
        hid[t] = fmaxf(s1, 0.f);
    }
    __syncthreads();
    if (t < 4) {
        float s2 = b2[t];
        for (int j = 0; j < 100; ++j) s2 = fmaf(hid[j], w2[j * 4 + t], s2);
        out[(size_t)g * 4 + t] = s2;
    }
}

// ---------------- launch ----------------

extern "C" void kernel_launch(void* const* d_in, const int* in_sizes, int n_in,
                              void* d_out, int out_size, void* d_ws, size_t ws_size,
                              hipStream_t stream) {
    const float* x   = (const float*)d_in[0];
    const float* Ws  = (const float*)d_in[1];
    const float* bs  = (const float*)d_in[2];
    const float* w1  = (const float*)d_in[3];
    const float* b1  = (const float*)d_in[4];
    const float* w2  = (const float*)d_in[5];
    const float* b2  = (const float*)d_in[6];
    const int*   ei  = (const int*)d_in[7];
    const int*   bat = (const int*)d_in[8];
    float* outp = (float*)d_out;

    char* p = (char*)d_ws;
    auto take = [&](size_t bytes) -> void* {
        void* r = (void*)p;
        p += (bytes + 255) & ~(size_t)255;
        return r;
    };
    int*      csr    = (int*)take((size_t)(N_NODES + 1) * 4);
    float*    dinv   = (float*)take((size_t)N_NODES * 4);
    int*      bfill  = (int*)take((size_t)NBUCK * 4);
    unsigned* tmp    = (unsigned*)take((size_t)NBUCK * CAP * 4);
    int*      ssrc   = (int*)take((size_t)N_EDGES * 4);
    ushort*   xb     = (ushort*)take((size_t)N_NODES * 128 * 2);
    ushort*   hbA    = (ushort*)take((size_t)N_NODES * 128 * 2);
    ushort*   hbB    = (ushort*)take((size_t)N_NODES * 128 * 2);
    ushort*   WT     = (ushort*)take((size_t)4 * 128 * 128 * 2);
    int*      gstart = (int*)take((size_t)(N_GRAPHS + 1) * 4);

    const int* row = ei;
    const int* col = ei + N_EDGES;

    hipMemsetAsync(bfill, 0, (size_t)NBUCK * 4, stream);

    front_kernel<<<FB_BIN + FB_WT, 1024, 0, stream>>>(row, col, bfill, tmp, Ws, WT);
    sort_kernel<<<NBUCK, 1024, 0, stream>>>(tmp, bfill, csr, dinv, ssrc);
    cvt_x<<<12500, 256, 0, stream>>>(x, dinv, xb, bat, gstart);

    // ping-pong: layer input and output must be DISTINCT buffers (blocks
    // gather from rows other blocks write). xb is dinv-prescaled.
    const ushort* hin = xb;
    ushort* hout = hbA;
    for (int L = 0; L < 4; ++L) {
        layer_kernel<<<(N_NODES + 127) / 128, 512, 0, stream>>>(
            hin, WT + (size_t)L * 128 * 128, bs + (size_t)L * 128, dinv,
            csr, ssrc, hout, (L < 3) ? 1 : 0);
        hin = hout;
        hout = (hout == hbA) ? hbB : hbA;
    }
    // after 4 layers: hin points at the final output buffer
    pool_mlp<<<N_GRAPHS, 256, 0, stream>>>(hin, gstart, w1, b1, w2, b2, outp);
}